// Round 9
// baseline (346.539 us; speedup 1.0000x reference)
//
#include <hip/hip_runtime.h>
#include <math.h>

#define NN 50000
#define NE 800000
#define INF_DIM 256
#define HIDF 64
#define NC 32
#define SLOPE 0.2f

__device__ __forceinline__ float elem8(const float4& a, const float4& b, int kk){
  switch(kk){
    case 0: return a.x; case 1: return a.y; case 2: return a.z; case 3: return a.w;
    case 4: return b.x; case 5: return b.y; case 6: return b.z; default: return b.w;
  }
}
#define FMA4(A,S,V) {A.x += (S)*(V).x; A.y += (S)*(V).y; A.z += (S)*(V).z; A.w += (S)*(V).w;}

// ============================ CSR build ============================

__global__ void k_zero(int* __restrict__ counts){
  int i = blockIdx.x*blockDim.x + threadIdx.x;
  if(i < NN) counts[i] = 0;
}

__global__ void k_hist(const int* __restrict__ dst, int* __restrict__ counts){
  int e = blockIdx.x*blockDim.x + threadIdx.x;
  if(e < NE) atomicAdd(&counts[dst[e]], 1);
}

__global__ void k_scan_a(const int* __restrict__ counts, int* __restrict__ rowstart,
                         int* __restrict__ blocksums){
  __shared__ int wsum[4];
  int tid = threadIdx.x;
  int idx = blockIdx.x*1024 + tid*4;
  int v0 = (idx+0<NN)?counts[idx+0]:0;
  int v1 = (idx+1<NN)?counts[idx+1]:0;
  int v2 = (idx+2<NN)?counts[idx+2]:0;
  int v3 = (idx+3<NN)?counts[idx+3]:0;
  int s0=v0, s1=s0+v1, s2=s1+v2, s3=s2+v3;
  int lane = tid & 63, w = tid >> 6;
  int x = s3;
  #pragma unroll
  for(int off=1; off<64; off<<=1){
    int y = __shfl_up(x, off, 64);
    if(lane >= off) x += y;
  }
  if(lane==63) wsum[w] = x;
  __syncthreads();
  int woff = 0;
  for(int i=0;i<w;i++) woff += wsum[i];
  int excl = woff + (x - s3);
  if(idx+0<NN) rowstart[idx+1] = excl + s0;
  if(idx+1<NN) rowstart[idx+2] = excl + s1;
  if(idx+2<NN) rowstart[idx+3] = excl + s2;
  if(idx+3<NN) rowstart[idx+4] = excl + s3;
  if(tid==0) blocksums[blockIdx.x] = wsum[0]+wsum[1]+wsum[2]+wsum[3];
}

__global__ void k_scan_b(const int* __restrict__ blocksums, int* __restrict__ blockoff){
  int lane = threadIdx.x;
  const int nb = (NN + 1023)/1024;
  int v = (lane<nb)? blocksums[lane] : 0;
  int x = v;
  #pragma unroll
  for(int off=1; off<64; off<<=1){
    int y = __shfl_up(x, off, 64);
    if(lane >= off) x += y;
  }
  if(lane<nb) blockoff[lane] = x - v;
}

__global__ void k_scan_c(const int* __restrict__ counts, int* __restrict__ rowstart,
                         const int* __restrict__ blockoff, int* __restrict__ cursor){
  int i = blockIdx.x*blockDim.x + threadIdx.x;
  if(i < NN){
    int incl = rowstart[i+1] + blockoff[i>>10];
    rowstart[i+1] = incl;
    cursor[i] = incl - counts[i];
    if(i==0) rowstart[0] = 0;
  }
}

__global__ void k_scatter(const int* __restrict__ src, const int* __restrict__ dst,
                          int* __restrict__ cursor, int* __restrict__ ssrc){
  int e = blockIdx.x*blockDim.x + threadIdx.x;
  if(e < NE){
    int d = dst[e];
    int pos = atomicAdd(&cursor[d], 1);
    ssrc[pos] = src[e];
  }
}

// ============================ GEMM 1: h1 = x @ W1, fused a_src/a_dst dots ===
// Pure-register streaming: no LDS, no barriers. 16 nodes/wave, grid 3125
// (12 waves/CU, VGPR~100 -> all resident). Lane (cg=lane&7, ng=lane>>3)
// owns nodes {nb0+ng, nb0+ng+8} x cols {cg*8..cg*8+7}. x double-buffered
// in 8-k slices, prefetched 2 slices (~500cyc of FMA) ahead. W per-lane
// vector loads (8 dup lanes merge in coalescer; 16KB L1-hot), 4-row
// rolling register window (row k+4 issued while computing row k).

__global__ __launch_bounds__(64) void k_gemm1(
    const float* __restrict__ x, const float* __restrict__ W,
    const float* __restrict__ a_s, const float* __restrict__ a_d,
    float* __restrict__ h, float* __restrict__ as_o, float* __restrict__ ad_o){
  int lane = threadIdx.x;
  int cg = lane & 7;
  int ng = lane >> 3;
  int nb0 = blockIdx.x*16;
  int n0 = nb0 + ng, n1 = nb0 + ng + 8;
  const float* xr0 = x + (size_t)(n0 < NN ? n0 : NN-1)*INF_DIM;
  const float* xr1 = x + (size_t)(n1 < NN ? n1 : NN-1)*INF_DIM;
  const float* wp = W + cg*8;

  float4 acc00 = make_float4(0.f,0.f,0.f,0.f), acc01 = acc00;
  float4 acc10 = acc00, acc11 = acc00;

  float4 xs[2][2][2];     // [slice parity][row][half]
  float4 wr[4][2];        // rolling W window [k&3][half]

  #pragma unroll
  for(int s=0;s<2;s++){
    xs[s][0][0] = *(const float4*)(xr0 + s*8);
    xs[s][0][1] = *(const float4*)(xr0 + s*8 + 4);
    xs[s][1][0] = *(const float4*)(xr1 + s*8);
    xs[s][1][1] = *(const float4*)(xr1 + s*8 + 4);
  }
  #pragma unroll
  for(int r=0;r<4;r++){
    wr[r][0] = *(const float4*)(wp + r*64);
    wr[r][1] = *(const float4*)(wp + r*64 + 4);
  }

  #pragma unroll 2
  for(int st=0; st<32; ++st){
    int buf = st & 1;
    #pragma unroll
    for(int kk=0; kk<8; ++kk){
      float xk0 = elem8(xs[buf][0][0], xs[buf][0][1], kk);
      float xk1 = elem8(xs[buf][1][0], xs[buf][1][1], kk);
      float4 wa = wr[kk & 3][0];
      float4 wb = wr[kk & 3][1];
      FMA4(acc00, xk0, wa) FMA4(acc01, xk0, wb)
      FMA4(acc10, xk1, wa) FMA4(acc11, xk1, wb)
      int knext = st*8 + kk + 4; if(knext > 255) knext = 255;
      wr[kk & 3][0] = *(const float4*)(wp + knext*64);
      wr[kk & 3][1] = *(const float4*)(wp + knext*64 + 4);
    }
    int sn = st + 2;
    if(sn < 32){
      xs[buf][0][0] = *(const float4*)(xr0 + sn*8);
      xs[buf][0][1] = *(const float4*)(xr0 + sn*8 + 4);
      xs[buf][1][0] = *(const float4*)(xr1 + sn*8);
      xs[buf][1][1] = *(const float4*)(xr1 + sn*8 + 4);
    }
  }

  float4 asA = *(const float4*)(a_s + cg*8), asB = *(const float4*)(a_s + cg*8 + 4);
  float4 adA = *(const float4*)(a_d + cg*8), adB = *(const float4*)(a_d + cg*8 + 4);
  float sv0 = acc00.x*asA.x + acc00.y*asA.y + acc00.z*asA.z + acc00.w*asA.w
            + acc01.x*asB.x + acc01.y*asB.y + acc01.z*asB.z + acc01.w*asB.w;
  float dv0 = acc00.x*adA.x + acc00.y*adA.y + acc00.z*adA.z + acc00.w*adA.w
            + acc01.x*adB.x + acc01.y*adB.y + acc01.z*adB.z + acc01.w*adB.w;
  float sv1 = acc10.x*asA.x + acc10.y*asA.y + acc10.z*asA.z + acc10.w*asA.w
            + acc11.x*asB.x + acc11.y*asB.y + acc11.z*asB.z + acc11.w*asB.w;
  float dv1 = acc10.x*adA.x + acc10.y*adA.y + acc10.z*adA.z + acc10.w*adA.w
            + acc11.x*adB.x + acc11.y*adB.y + acc11.z*adB.z + acc11.w*adB.w;
  #pragma unroll
  for(int mk=1; mk<8; mk<<=1){
    sv0 += __shfl_xor(sv0, mk, 64);
    dv0 += __shfl_xor(dv0, mk, 64);
    sv1 += __shfl_xor(sv1, mk, 64);
    dv1 += __shfl_xor(dv1, mk, 64);
  }
  if(n0 < NN){
    *(float4*)(h + (size_t)n0*HIDF + cg*8)     = acc00;
    *(float4*)(h + (size_t)n0*HIDF + cg*8 + 4) = acc01;
    if(cg==0){ as_o[n0]=sv0; ad_o[n0]=dv0; }
  }
  if(n1 < NN){
    *(float4*)(h + (size_t)n1*HIDF + cg*8)     = acc10;
    *(float4*)(h + (size_t)n1*HIDF + cg*8 + 4) = acc11;
    if(cg==0){ as_o[n1]=sv1; ad_o[n1]=dv1; }
  }
}

// ============================ Aggregation layer 1 ===========================

__global__ __launch_bounds__(256) void k_agg1(
    const float* __restrict__ h1, const float* __restrict__ as1, const float* __restrict__ ad1,
    const int* __restrict__ rowstart, const int* __restrict__ ssrc,
    float* __restrict__ r1){
  int lane = threadIdx.x & 63;
  int n = blockIdx.x*4 + (threadIdx.x >> 6);
  int rs = rowstart[n], re = rowstart[n+1];
  float adn = ad1[n];
  float m = -1e30f, l = 0.f, acc = 0.f;
  for(int base=rs; base<re; base+=64){
    int cnt = re - base; if(cnt > 64) cnt = 64;
    int s = 0; float z = -1e30f;
    if(lane < cnt){
      s = ssrc[base+lane];
      float zz = as1[s] + adn;
      z = zz > 0.f ? zz : SLOPE*zz;
    }
    float cm = z;
    #pragma unroll
    for(int off=32; off>=1; off>>=1) cm = fmaxf(cm, __shfl_xor(cm, off, 64));
    float nm = fmaxf(m, cm);
    float sc = __expf(m - nm);
    float p = (lane<cnt) ? __expf(z - nm) : 0.f;
    float cs = p;
    #pragma unroll
    for(int off=32; off>=1; off>>=1) cs += __shfl_xor(cs, off, 64);
    l = l*sc + cs;
    acc *= sc;
    int e = 0;
    for(; e+4<=cnt; e+=4){
      int   se0 = __shfl(s, e,   64), se1 = __shfl(s, e+1, 64);
      int   se2 = __shfl(s, e+2, 64), se3 = __shfl(s, e+3, 64);
      float pe0 = __shfl(p, e,   64), pe1 = __shfl(p, e+1, 64);
      float pe2 = __shfl(p, e+2, 64), pe3 = __shfl(p, e+3, 64);
      float v0 = h1[(size_t)se0*HIDF + lane];
      float v1 = h1[(size_t)se1*HIDF + lane];
      float v2 = h1[(size_t)se2*HIDF + lane];
      float v3 = h1[(size_t)se3*HIDF + lane];
      acc += pe0*v0; acc += pe1*v1; acc += pe2*v2; acc += pe3*v3;
    }
    for(; e<cnt; ++e){
      int   se = __shfl(s, e, 64);
      float pe = __shfl(p, e, 64);
      acc += pe * h1[(size_t)se*HIDF + lane];
    }
    m = nm;
  }
  float o = (l > 0.f) ? acc/l : 0.f;
  r1[(size_t)n*HIDF + lane] = fmaxf(o, 0.f);
}

// ============================ GEMM 2: h2 = r1 @ W2, fused a dots ============
// Same pure-register streaming structure. 16 nodes/wave, lane = (ng=lane>>2,
// cg=lane&3), 1 node x 8 cols per lane. W2 (8KB) L1-hot rolling window.

__global__ __launch_bounds__(64) void k_gemm2(
    const float* __restrict__ r1, const float* __restrict__ W2,
    const float* __restrict__ a_s, const float* __restrict__ a_d,
    float* __restrict__ h2, float* __restrict__ as_o, float* __restrict__ ad_o){
  int lane = threadIdx.x;
  int cg = lane & 3;
  int ng = lane >> 2;
  int n = blockIdx.x*16 + ng;
  const float* xrow = r1 + (size_t)(n < NN ? n : NN-1)*HIDF;
  const float* wp = W2 + cg*8;

  float4 acc0 = make_float4(0.f,0.f,0.f,0.f), acc1 = acc0;
  float4 xs[2][2];
  float4 wr[4][2];

  #pragma unroll
  for(int s=0;s<2;s++){
    xs[s][0] = *(const float4*)(xrow + s*8);
    xs[s][1] = *(const float4*)(xrow + s*8 + 4);
  }
  #pragma unroll
  for(int r=0;r<4;r++){
    wr[r][0] = *(const float4*)(wp + r*32);
    wr[r][1] = *(const float4*)(wp + r*32 + 4);
  }

  #pragma unroll 2
  for(int st=0; st<8; ++st){
    int buf = st & 1;
    #pragma unroll
    for(int kk=0; kk<8; ++kk){
      float xk = elem8(xs[buf][0], xs[buf][1], kk);
      float4 wa = wr[kk & 3][0];
      float4 wb = wr[kk & 3][1];
      FMA4(acc0, xk, wa) FMA4(acc1, xk, wb)
      int knext = st*8 + kk + 4; if(knext > 63) knext = 63;
      wr[kk & 3][0] = *(const float4*)(wp + knext*32);
      wr[kk & 3][1] = *(const float4*)(wp + knext*32 + 4);
    }
    int sn = st + 2;
    if(sn < 8){
      xs[buf][0] = *(const float4*)(xrow + sn*8);
      xs[buf][1] = *(const float4*)(xrow + sn*8 + 4);
    }
  }

  float4 asA = *(const float4*)(a_s + cg*8), asB = *(const float4*)(a_s + cg*8 + 4);
  float4 adA = *(const float4*)(a_d + cg*8), adB = *(const float4*)(a_d + cg*8 + 4);
  float sv = acc0.x*asA.x + acc0.y*asA.y + acc0.z*asA.z + acc0.w*asA.w
           + acc1.x*asB.x + acc1.y*asB.y + acc1.z*asB.z + acc1.w*asB.w;
  float dv = acc0.x*adA.x + acc0.y*adA.y + acc0.z*adA.z + acc0.w*adA.w
           + acc1.x*adB.x + acc1.y*adB.y + acc1.z*adB.z + acc1.w*adB.w;
  #pragma unroll
  for(int mk=1; mk<4; mk<<=1){
    sv += __shfl_xor(sv, mk, 64);
    dv += __shfl_xor(dv, mk, 64);
  }
  if(n < NN){
    *(float4*)(h2 + (size_t)n*NC + cg*8)     = acc0;
    *(float4*)(h2 + (size_t)n*NC + cg*8 + 4) = acc1;
    if(cg==0){ as_o[n]=sv; ad_o[n]=dv; }
  }
}

// ============================ Aggregation layer 2 ===========================

__global__ __launch_bounds__(256) void k_agg2(
    const float* __restrict__ h2, const float* __restrict__ as2, const float* __restrict__ ad2,
    const int* __restrict__ rowstart, const int* __restrict__ ssrc,
    float* __restrict__ out){
  int tid = threadIdx.x;
  int c = tid & 31;
  int n = blockIdx.x*8 + (tid >> 5);
  int rs = rowstart[n], re = rowstart[n+1];
  float adn = ad2[n];
  float m = -1e30f, l = 0.f, acc = 0.f;
  for(int base=rs; base<re; base+=32){
    int cnt = re - base; if(cnt > 32) cnt = 32;
    int s = 0; float z = -1e30f;
    if(c < cnt){
      s = ssrc[base+c];
      float zz = as2[s] + adn;
      z = zz > 0.f ? zz : SLOPE*zz;
    }
    float cm = z;
    #pragma unroll
    for(int off=16; off>=1; off>>=1) cm = fmaxf(cm, __shfl_xor(cm, off, 32));
    float nm = fmaxf(m, cm);
    float sc = __expf(m - nm);
    float p = (c<cnt) ? __expf(z - nm) : 0.f;
    float cs = p;
    #pragma unroll
    for(int off=16; off>=1; off>>=1) cs += __shfl_xor(cs, off, 32);
    l = l*sc + cs;
    acc *= sc;
    int e = 0;
    for(; e+4<=cnt; e+=4){
      int   se0 = __shfl(s, e,   32), se1 = __shfl(s, e+1, 32);
      int   se2 = __shfl(s, e+2, 32), se3 = __shfl(s, e+3, 32);
      float pe0 = __shfl(p, e,   32), pe1 = __shfl(p, e+1, 32);
      float pe2 = __shfl(p, e+2, 32), pe3 = __shfl(p, e+3, 32);
      float v0 = h2[(size_t)se0*NC + c];
      float v1 = h2[(size_t)se1*NC + c];
      float v2 = h2[(size_t)se2*NC + c];
      float v3 = h2[(size_t)se3*NC + c];
      acc += pe0*v0; acc += pe1*v1; acc += pe2*v2; acc += pe3*v3;
    }
    for(; e<cnt; ++e){
      int   se = __shfl(s, e, 32);
      float pe = __shfl(p, e, 32);
      acc += pe * h2[(size_t)se*NC + c];
    }
    m = nm;
  }
  out[(size_t)n*NC + c] = (l > 0.f) ? acc/l : 0.f;
}

// ============================ launch ============================

extern "C" void kernel_launch(void* const* d_in, const int* in_sizes, int n_in,
                              void* d_out, int out_size, void* d_ws, size_t ws_size,
                              hipStream_t stream){
  const float* x   = (const float*)d_in[0];
  const int*   ei  = (const int*)d_in[1];
  const float* W1  = (const float*)d_in[2];
  const float* a1s = (const float*)d_in[3];
  const float* a1d = (const float*)d_in[4];
  const float* W2  = (const float*)d_in[5];
  const float* a2s = (const float*)d_in[6];
  const float* a2d = (const float*)d_in[7];
  const int* srcIdx = ei;
  const int* dstIdx = ei + NE;
  float* out = (float*)d_out;

  char* wsp = (char*)d_ws;
  size_t off = 0;
  auto alloc = [&](size_t bytes)->void*{
    void* p = wsp + off;
    off = (off + bytes + 255) & ~(size_t)255;
    return p;
  };
  int* counts    = (int*)alloc((size_t)NN*sizeof(int));
  int* rowstart  = (int*)alloc((size_t)(NN+1)*sizeof(int));
  int* cursor    = (int*)alloc((size_t)NN*sizeof(int));
  int* blocksums = (int*)alloc(64*sizeof(int));
  int* blockoff  = (int*)alloc(64*sizeof(int));
  int* ssrc      = (int*)alloc((size_t)NE*sizeof(int));
  float* h1      = (float*)alloc((size_t)NN*HIDF*sizeof(float));
  float* as1     = (float*)alloc((size_t)NN*sizeof(float));
  float* ad1     = (float*)alloc((size_t)NN*sizeof(float));
  float* r1      = (float*)alloc((size_t)NN*HIDF*sizeof(float));
  float* h2  = h1;
  float* as2 = as1;
  float* ad2 = ad1;

  k_zero   <<<(NN+255)/256, 256, 0, stream>>>(counts);
  k_hist   <<<(NE+255)/256, 256, 0, stream>>>(dstIdx, counts);
  k_scan_a <<<(NN+1023)/1024, 256, 0, stream>>>(counts, rowstart, blocksums);
  k_scan_b <<<1, 64, 0, stream>>>(blocksums, blockoff);
  k_scan_c <<<(NN+255)/256, 256, 0, stream>>>(counts, rowstart, blockoff, cursor);
  k_scatter<<<(NE+255)/256, 256, 0, stream>>>(srcIdx, dstIdx, cursor, ssrc);

  k_gemm1<<<(NN+15)/16, 64, 0, stream>>>(x, W1, a1s, a1d, h1, as1, ad1);
  k_agg1 <<<NN/4, 256, 0, stream>>>(h1, as1, ad1, rowstart, ssrc, r1);

  k_gemm2<<<(NN+15)/16, 64, 0, stream>>>(r1, W2, a2s, a2d, h2, as2, ad2);
  k_agg2 <<<NN/8, 256, 0, stream>>>(h2, as2, ad2, rowstart, ssrc, out);
}